// Round 14
// baseline (161.950 us; speedup 1.0000x reference)
//
#include <hip/hip_runtime.h>
#include <hip/hip_bf16.h>
#include <math.h>

typedef __attribute__((ext_vector_type(8))) short short8;
typedef __attribute__((ext_vector_type(4))) float floatx4;

__device__ __forceinline__ unsigned short f2b(float f) {
  unsigned int u = __builtin_bit_cast(unsigned int, f);
  u += 0x7fffu + ((u >> 16) & 1u);
  return (unsigned short)(u >> 16);
}
__device__ __forceinline__ float b2f(unsigned short s) {
  unsigned int u = ((unsigned int)s) << 16;
  return __builtin_bit_cast(float, u);
}
__device__ __forceinline__ float blo(unsigned int u) {
  return __builtin_bit_cast(float, u << 16);
}
__device__ __forceinline__ float bhi(unsigned int u) {
  return __builtin_bit_cast(float, u & 0xffff0000u);
}
__device__ __forceinline__ float sigm(float v) { return 1.f / (1.f + __expf(-v)); }
__device__ __forceinline__ float tanh_fast(float y) {
  float t = __expf(2.f * y);
  return 1.f - 2.f / (t + 1.f);
}

// ---------------------------------------------------------------------------
// Edge preprocessing: dtype detect -> bucket radix partition -> CSR
// ---------------------------------------------------------------------------
__global__ __launch_bounds__(1024) void detect_kernel(const unsigned int* __restrict__ ei,
                                                      long long n_u32, int* __restrict__ flag) {
  __shared__ int any;
  if (threadIdx.x == 0) any = 0;
  __syncthreads();
  int nz = 0;
  for (int rep = 0; rep < 4; ++rep) {
    long long idx = 2LL * (threadIdx.x + rep * 1024) + 1;
    if (idx < n_u32 && ei[idx] != 0u) nz = 1;
  }
  if (nz) atomicOr(&any, 1);
  __syncthreads();
  if (threadIdx.x == 0) *flag = any;  // 1 -> int32 data, 0 -> int64 data
}

__device__ __forceinline__ int load_dst(const void* ei, int E, int flag, int i) {
  if (flag == 0) return (int)((const long long*)ei)[(long long)E + i];
  return ((const int*)ei)[E + i];
}
__device__ __forceinline__ int load_src(const void* ei, int E, int flag, int i) {
  if (flag == 0) return (int)((const long long*)ei)[i];
  return ((const int*)ei)[i];
}

__global__ __launch_bounds__(256) void bucket_hist(const void* __restrict__ ei, int E,
                                                   const int* __restrict__ flag,
                                                   int* __restrict__ bucketCnt, int nbk) {
  __shared__ int h[512];
  for (int i = threadIdx.x; i < nbk; i += 256) h[i] = 0;
  __syncthreads();
  int fl = *flag;
  int gid = blockIdx.x * 256 + threadIdx.x;
  int stride = gridDim.x * 256;
  for (int i = gid; i < E; i += stride) {
    int d = load_dst(ei, E, fl, i);
    atomicAdd(&h[d >> 7], 1);
  }
  __syncthreads();
  for (int i = threadIdx.x; i < nbk; i += 256)
    if (h[i]) atomicAdd(&bucketCnt[i], h[i]);
}

__global__ __launch_bounds__(64) void bucket_scan(const int* __restrict__ bucketCnt,
                                                  int* __restrict__ bucketBase,
                                                  int* __restrict__ bucketCursor, int nbk) {
  int lane = threadIdx.x;
  int carry = 0;
  for (int base = 0; base < nbk; base += 64) {
    int i = base + lane;
    int v = (i < nbk) ? bucketCnt[i] : 0;
    int s = v;
    #pragma unroll
    for (int ofs = 1; ofs < 64; ofs <<= 1) {
      int t = __shfl_up(s, ofs, 64);
      if (lane >= ofs) s += t;
    }
    if (i < nbk) {
      int ex = s - v + carry;
      bucketBase[i] = ex;
      bucketCursor[i] = ex;
    }
    carry += __shfl(s, 63, 64);
  }
  if (lane == 0) bucketBase[nbk] = carry;   // == E
}

__global__ __launch_bounds__(256) void partition_kernel(const void* __restrict__ ei, int E,
                                                        const int* __restrict__ flag,
                                                        int* __restrict__ bucketCursor,
                                                        unsigned long long* __restrict__ pairBuf,
                                                        int nbk) {
  __shared__ int h[512];
  __shared__ int base[512];
  int tid = threadIdx.x;
  for (int i = tid; i < nbk; i += 256) h[i] = 0;
  __syncthreads();
  int fl = *flag;
  int tile0 = blockIdx.x * 4096;
  int sarr[16], darr[16], rank[16];
  #pragma unroll
  for (int k = 0; k < 16; ++k) {
    int idx = tile0 + tid + k * 256;
    rank[k] = -1;
    if (idx < E) {
      sarr[k] = load_src(ei, E, fl, idx);
      darr[k] = load_dst(ei, E, fl, idx);
      rank[k] = atomicAdd(&h[darr[k] >> 7], 1);
    }
  }
  __syncthreads();
  for (int i = tid; i < nbk; i += 256)
    base[i] = h[i] ? atomicAdd(&bucketCursor[i], h[i]) : 0;
  __syncthreads();
  #pragma unroll
  for (int k = 0; k < 16; ++k) {
    if (rank[k] >= 0) {
      int bk = darr[k] >> 7;
      pairBuf[(size_t)base[bk] + rank[k]] =
          ((unsigned long long)(unsigned)darr[k] << 32) | (unsigned)sarr[k];
    }
  }
}

__global__ __launch_bounds__(256) void csr_build(const unsigned long long* __restrict__ pairBuf,
                                                 const int* __restrict__ bucketBase,
                                                 int* __restrict__ off, int* __restrict__ csr,
                                                 int n, int E, int nbk) {
  __shared__ int cnt[128];
  __shared__ int start[128];
  __shared__ int wtot[4];
  int bk = blockIdx.x;
  int tid = threadIdx.x;
  int lo = bucketBase[bk], hi = bucketBase[bk + 1];
  int node0 = bk << 7;
  if (tid < 128) cnt[tid] = 0;
  __syncthreads();
  for (int i = lo + tid; i < hi; i += 256) {
    int d = (int)(pairBuf[i] >> 32);
    atomicAdd(&cnt[d - node0], 1);
  }
  __syncthreads();
  {
    int v = (tid < 128) ? cnt[tid] : 0;
    int s = v;
    #pragma unroll
    for (int ofs = 1; ofs < 64; ofs <<= 1) {
      int t = __shfl_up(s, ofs, 64);
      if ((tid & 63) >= ofs) s += t;
    }
    if ((tid & 63) == 63) wtot[tid >> 6] = s;
    __syncthreads();
    if (tid < 128) {
      int pre = (tid >> 6) ? wtot[0] : 0;
      start[tid] = s - v + pre;
    }
  }
  __syncthreads();
  int nNodes = n - node0;
  if (nNodes > 128) nNodes = 128;
  if (tid < nNodes) off[node0 + tid] = lo + start[tid];
  if (bk == nbk - 1 && tid == 0) off[n] = E;
  if (tid < 128) cnt[tid] = 0;
  __syncthreads();
  for (int i = lo + tid; i < hi; i += 256) {
    unsigned long long pr = pairBuf[i];
    int s = (int)(unsigned)pr;
    int ld = (int)(pr >> 32) - node0;
    int r = atomicAdd(&cnt[ld], 1);
    csr[lo + start[ld] + r] = s;
  }
}

// ---------------------------------------------------------------------------
// Weights -> bf16 in MFMA FRAGMENT ORDER.
// ---------------------------------------------------------------------------
__global__ __launch_bounds__(256) void wprep(const float* __restrict__ Wl,
                                             const float* __restrict__ Wr,
                                             const float* __restrict__ W1,
                                             const float* __restrict__ W2,
                                             unsigned short* __restrict__ Btfxw,
                                             unsigned short* __restrict__ Btf1,
                                             unsigned short* __restrict__ Btf2) {
  int gid = blockIdx.x * 256 + threadIdx.x;   // 16384 total
  if (gid < 4096) {                           // xw
    int lane = gid & 63, fid = gid >> 6;
    int l15 = lane & 15, lhi = lane >> 4;
    int kk = fid & 3, nt = (fid >> 2) & 3, w = fid >> 4;
    int col = w * 64 + nt * 16 + l15;
    int k0 = kk * 32 + lhi * 8;
    #pragma unroll
    for (int e = 0; e < 8; ++e) {
      float v = (col < 128) ? Wl[(k0 + e) * 128 + col] : Wr[(k0 + e) * 128 + (col - 128)];
      Btfxw[(size_t)gid * 8 + e] = f2b(v);
    }
  } else if (gid < 12288) {                   // W1
    int g = gid - 4096;
    int lane = g & 63, fid = g >> 6;
    int l15 = lane & 15, lhi = lane >> 4;
    int kk = fid & 1, ks = (fid >> 1) & 3, nt = (fid >> 3) & 3, w = fid >> 5;
    int col = (nt < 2) ? (w * 32 + nt * 16 + l15) : (128 + w * 32 + (nt - 2) * 16 + l15);
    int k0 = ks * 64 + kk * 32 + lhi * 8;
    #pragma unroll
    for (int e = 0; e < 8; ++e)
      Btf1[(size_t)g * 8 + e] = f2b(W1[(k0 + e) * 256 + col]);
  } else {                                    // W2
    int g = gid - 12288;
    int lane = g & 63, fid = g >> 6;
    int l15 = lane & 15, lhi = lane >> 4;
    int kk = fid & 1, ks = (fid >> 1) & 3, nt = (fid >> 3) & 1, w = fid >> 4;
    int col = w * 32 + nt * 16 + l15;
    int k0 = ks * 64 + kk * 32 + lhi * 8;
    #pragma unroll
    for (int e = 0; e < 8; ++e)
      Btf2[(size_t)g * 8 + e] = f2b(W2[(k0 + e) * 128 + col]);
  }
}

// ---------------------------------------------------------------------------
// xl|xr = x @ [Wl|Wr].  BM=32, LDS = A only (8 KB).  B fragments from L2
// with one-step register double-buffer (bcur/bnext).
// ---------------------------------------------------------------------------
__global__ __launch_bounds__(256) void gemm_xw(const float* __restrict__ x,
                                               const unsigned short* __restrict__ Btf,
                                               unsigned short* __restrict__ xl,
                                               unsigned short* __restrict__ xr, int n) {
  __shared__ char As[32 * 256];    // 32 rows x 128 bf16, swizzled
  int t = threadIdx.x;
  int w = t >> 6, l = t & 63;
  int row0 = blockIdx.x * 32;
  int l15 = l & 15, lhi = l >> 4;

  // stage A from f32: src linear, dest swizzled (rule #21)
  #pragma unroll
  for (int u_ = 0; u_ < 2; ++u_) {
    int unit = t + u_ * 256;
    int r = unit >> 4, slot = unit & 15;
    int grow = row0 + r;
    uint4 o = make_uint4(0, 0, 0, 0);
    if (grow < n) {
      const float* s = x + (size_t)grow * 128 + slot * 8;
      float4 f0 = *(const float4*)s, f1 = *(const float4*)(s + 4);
      o.x = (unsigned)f2b(f0.x) | ((unsigned)f2b(f0.y) << 16);
      o.y = (unsigned)f2b(f0.z) | ((unsigned)f2b(f0.w) << 16);
      o.z = (unsigned)f2b(f1.x) | ((unsigned)f2b(f1.y) << 16);
      o.w = (unsigned)f2b(f1.z) | ((unsigned)f2b(f1.w) << 16);
    }
    *(uint4*)(As + r * 256 + ((slot * 16) ^ ((r & 7) << 4))) = o;
  }
  __syncthreads();

  floatx4 acc[2][4];
  #pragma unroll
  for (int mt = 0; mt < 2; ++mt)
    #pragma unroll
    for (int nt = 0; nt < 4; ++nt) acc[mt][nt] = (floatx4){0.f, 0.f, 0.f, 0.f};

  short8 bcur[4], bnext[4];
  #pragma unroll
  for (int nt = 0; nt < 4; ++nt)
    bcur[nt] = *(const short8*)(Btf + (((size_t)(w * 4 + nt) * 4 + 0) * 64 + l) * 8);

  #pragma unroll 1
  for (int kk = 0; kk < 4; ++kk) {
    if (kk < 3) {
      #pragma unroll
      for (int nt = 0; nt < 4; ++nt)
        bnext[nt] = *(const short8*)(Btf + (((size_t)(w * 4 + nt) * 4 + kk + 1) * 64 + l) * 8);
    }
    int ko = kk * 64 + lhi * 16;
    short8 a[2];
    #pragma unroll
    for (int mt = 0; mt < 2; ++mt) {
      int r = mt * 16 + l15;
      a[mt] = *(const short8*)(As + r * 256 + (ko ^ ((r & 7) << 4)));
    }
    #pragma unroll
    for (int nt = 0; nt < 4; ++nt)
      #pragma unroll
      for (int mt = 0; mt < 2; ++mt)
        acc[mt][nt] = __builtin_amdgcn_mfma_f32_16x16x32_bf16(a[mt], bcur[nt], acc[mt][nt], 0, 0, 0);
    if (kk < 3) {
      #pragma unroll
      for (int nt = 0; nt < 4; ++nt) bcur[nt] = bnext[nt];
    }
  }

  #pragma unroll
  for (int mt = 0; mt < 2; ++mt)
    #pragma unroll
    for (int nt = 0; nt < 4; ++nt) {
      int col = w * 64 + nt * 16 + l15;
      int rbase = row0 + mt * 16 + lhi * 4;
      #pragma unroll
      for (int j = 0; j < 4; ++j) {
        int row = rbase + j;
        if (row >= n) continue;
        unsigned short v = f2b(acc[mt][nt][j]);
        if (col < 128) xl[(size_t)row * 128 + col] = v;
        else           xr[(size_t)row * 128 + (col - 128)] = v;
      }
    }
}

// ---------------------------------------------------------------------------
// Node pass: one wave per node; 2 edges/pass (lane<32 edge i, lane>=32 edge
// i+1; lane&31 owns dims 4hl..4hl+3, head reduce = shfl 1,2,4).
// GATHER PIPELINE: 8 uint2 loads in flight (16 edges) -> one L3 latency per
// batch instead of per pass (node kernel was latency-bound, r13 analysis).
// Self loop = virtual edge at slot 0 of the first chunk.
// ---------------------------------------------------------------------------
__global__ __launch_bounds__(256) void node_kernel(const unsigned int* __restrict__ xl32,
                                                   const unsigned int* __restrict__ xr32,
                                                   const float* __restrict__ att,
                                                   const float* __restrict__ bias,
                                                   const int* __restrict__ off,
                                                   const int* __restrict__ csr,
                                                   unsigned int* __restrict__ fout, int n) {
  int wid = threadIdx.x >> 6, lane = threadIdx.x & 63;
  int node = blockIdx.x * 4 + wid;
  if (node >= n) return;
  int hl = lane & 31;
  bool upper = lane >= 32;
  const float LOG2E = 1.44269504f;
  float4 av = *(const float4*)(att + hl * 4);
  float a0 = av.x * LOG2E, a1 = av.y * LOG2E, a2 = av.z * LOG2E, a3 = av.w * LOG2E;
  uint2 xrp = *(const uint2*)(xr32 + node * 64 + hl * 2);
  float xr0 = blo(xrp.x), xr1 = bhi(xrp.x);
  float xr2 = blo(xrp.y), xr3 = bhi(xrp.y);
  float num0 = 0.f, num1 = 0.f, num2 = 0.f, num3 = 0.f, den = 0.f;
  int beg = off[node], end = off[node + 1];
  int tot = end - beg + 1;   // +1 virtual self loop at slot 0

  auto comp = [&](uint2 g, bool hiValid) {
    float x0 = blo(g.x), x1 = bhi(g.x), x2 = blo(g.y), x3 = bhi(g.y);
    float m0 = x0 + xr0, m1 = x1 + xr1, m2 = x2 + xr2, m3 = x3 + xr3;
    float l0 = fmaxf(m0, 0.2f * m0), l1 = fmaxf(m1, 0.2f * m1);
    float l2 = fmaxf(m2, 0.2f * m2), l3 = fmaxf(m3, 0.2f * m3);
    float p = l0 * a0;
    p = fmaf(l1, a1, p);
    p = fmaf(l2, a2, p);
    p = fmaf(l3, a3, p);
    p += __shfl_xor(p, 1, 64);
    p += __shfl_xor(p, 2, 64);
    p += __shfl_xor(p, 4, 64);
    float wgt = __builtin_amdgcn_exp2f(p);
    if (upper && !hiValid) wgt = 0.f;
    num0 = fmaf(wgt, x0, num0);
    num1 = fmaf(wgt, x1, num1);
    num2 = fmaf(wgt, x2, num2);
    num3 = fmaf(wgt, x3, num3);
    den += wgt;
  };

  auto gather = [&](int my, int i) -> uint2 {
    int sl = __builtin_amdgcn_readlane(my, i);
    int sh = __builtin_amdgcn_readlane(my, i + 1);
    int s = upper ? sh : sl;
    return *(const uint2*)(xl32 + ((unsigned)s << 6) + (unsigned)(hl << 1));
  };

  for (int j0 = 0; j0 < tot; j0 += 64) {
    int cnt = tot - j0;
    if (cnt > 64) cnt = 64;
    int my = node;
    if (j0 + lane > 0 && lane < cnt) my = csr[beg + j0 + lane - 1];
    int i = 0;
    // batched: 8 loads in flight (16 edges)
    for (; i + 16 <= cnt; i += 16) {
      uint2 g[8];
      #pragma unroll
      for (int k = 0; k < 8; ++k) g[k] = gather(my, i + 2 * k);
      #pragma unroll
      for (int k = 0; k < 8; ++k) comp(g[k], true);
    }
    // pair tail
    for (; i + 2 <= cnt; i += 2) comp(gather(my, i), true);
    // odd tail
    if (i < cnt) {
      int sl = __builtin_amdgcn_readlane(my, i);
      int s = upper ? node : sl;
      uint2 g = *(const uint2*)(xl32 + ((unsigned)s << 6) + (unsigned)(hl << 1));
      comp(g, false);
    }
  }

  // merge the two halves (lane l and l^32 hold the same dims)
  num0 += __shfl_xor(num0, 32, 64);
  num1 += __shfl_xor(num1, 32, 64);
  num2 += __shfl_xor(num2, 32, 64);
  num3 += __shfl_xor(num3, 32, 64);
  den  += __shfl_xor(den, 32, 64);

  if (!upper) {
    float inv = 1.f / (den + 1e-16f);
    float4 bv = *(const float4*)(bias + hl * 4);
    float v0 = num0 * inv + bv.x;
    float v1 = num1 * inv + bv.y;
    float v2 = num2 * inv + bv.z;
    float v3 = num3 * inv + bv.w;
    uint2 o;
    o.x = (unsigned)f2b(sigm(v0)) | ((unsigned)f2b(sigm(v1)) << 16);
    o.y = (unsigned)f2b(sigm(v2)) | ((unsigned)f2b(sigm(v3)) << 16);
    *(uint2*)(fout + node * 64 + hl * 2) = o;
  }
}

// ---------------------------------------------------------------------------
// Fused GRU GEMMs.  BM=32, LDS = A only (16 KB), 1563 blocks.
// B fragments from L2 with one-step register double-buffer.
// Phase1 wave w: cols {w*32..} U {128+w*32..} -> u gate stays in registers.
// ---------------------------------------------------------------------------
__global__ __launch_bounds__(256) void gemm_fused(const unsigned short* __restrict__ fbuf,
                                                  const float* __restrict__ hf,
                                                  const unsigned short* __restrict__ Btf1,
                                                  const unsigned short* __restrict__ Btf2,
                                                  const float* __restrict__ b1,
                                                  const float* __restrict__ b2,
                                                  float* __restrict__ out, int n) {
  __shared__ char As[32 * 512];           // [f|h] 32 rows x 256 bf16, swizzled
  int t = threadIdx.x;
  int w = t >> 6, l = t & 63;
  int row0 = blockIdx.x * 32;
  int l15 = l & 15, lhi = l >> 4;

  // stage A = [f | h]: src linear, dest swizzled
  #pragma unroll
  for (int u_ = 0; u_ < 4; ++u_) {
    int unit = t + u_ * 256;
    int r = unit >> 5, slot = unit & 31;
    int koff = slot * 16;
    int grow = row0 + r;
    uint4 v = make_uint4(0, 0, 0, 0);
    if (grow < n) {
      if (koff < 256) {
        v = *(const uint4*)(fbuf + (size_t)grow * 128 + koff / 2);
      } else {
        const float* s = hf + (size_t)grow * 128 + (koff - 256) / 2;
        float4 f0 = *(const float4*)s, f1 = *(const float4*)(s + 4);
        v.x = (unsigned)f2b(f0.x) | ((unsigned)f2b(f0.y) << 16);
        v.y = (unsigned)f2b(f0.z) | ((unsigned)f2b(f0.w) << 16);
        v.z = (unsigned)f2b(f1.x) | ((unsigned)f2b(f1.y) << 16);
        v.w = (unsigned)f2b(f1.z) | ((unsigned)f2b(f1.w) << 16);
      }
    }
    *(uint4*)(As + r * 512 + (koff ^ ((r & 7) << 4))) = v;
  }
  __syncthreads();

  // ---- phase 1: K=256, N=256; 8 steps of K=32 ----
  floatx4 acc[2][4];
  #pragma unroll
  for (int mt = 0; mt < 2; ++mt)
    #pragma unroll
    for (int nt = 0; nt < 4; ++nt) acc[mt][nt] = (floatx4){0.f, 0.f, 0.f, 0.f};

  short8 bcur[4], bnext[4];
  #pragma unroll
  for (int nt = 0; nt < 4; ++nt)
    bcur[nt] = *(const short8*)(Btf1 + (((size_t)(w * 4 + nt) * 8 + 0) * 64 + l) * 8);

  #pragma unroll 1
  for (int step = 0; step < 8; ++step) {
    if (step < 7) {
      #pragma unroll
      for (int nt = 0; nt < 4; ++nt)
        bnext[nt] = *(const short8*)(Btf1 + (((size_t)(w * 4 + nt) * 8 + step + 1) * 64 + l) * 8);
    }
    int ka = step * 64 + lhi * 16;
    short8 a[2];
    #pragma unroll
    for (int mt = 0; mt < 2; ++mt) {
      int r = mt * 16 + l15;
      a[mt] = *(const short8*)(As + r * 512 + (ka ^ ((r & 7) << 4)));
    }
    #pragma unroll
    for (int nt = 0; nt < 4; ++nt)
      #pragma unroll
      for (int mt = 0; mt < 2; ++mt)
        acc[mt][nt] = __builtin_amdgcn_mfma_f32_16x16x32_bf16(a[mt], bcur[nt], acc[mt][nt], 0, 0, 0);
    if (step < 7) {
      #pragma unroll
      for (int nt = 0; nt < 4; ++nt) bcur[nt] = bnext[nt];
    }
  }
  __syncthreads();   // all waves done reading As (h half) before overwrite

  // phase-1 epilogue: r-cols -> rh overwrites h half of As (swizzled);
  // u-cols stay in registers (layout matches phase-2 accumulator).
  float us[2][2][4];
  #pragma unroll
  for (int mt = 0; mt < 2; ++mt)
    #pragma unroll
    for (int nt = 0; nt < 4; ++nt) {
      #pragma unroll
      for (int j = 0; j < 4; ++j) {
        int rloc = mt * 16 + lhi * 4 + j;
        if (nt < 2) {
          int col = w * 32 + nt * 16 + l15;
          float s = sigm(acc[mt][nt][j] + b1[col]);
          int byteoff = (256 + col * 2) ^ ((rloc & 7) << 4);
          char* p = As + rloc * 512 + byteoff;
          unsigned short hv = *(unsigned short*)p;
          *(unsigned short*)p = f2b(s * b2f(hv));
        } else {
          int col = 128 + w * 32 + (nt - 2) * 16 + l15;
          us[mt][nt - 2][j] = sigm(acc[mt][nt][j] + b1[col]);
        }
      }
    }
  __syncthreads();

  // ---- phase 2: K=256, N=128; wave w owns cols w*32..+31 ----
  floatx4 acc2[2][2];
  #pragma unroll
  for (int mt = 0; mt < 2; ++mt)
    #pragma unroll
    for (int nt = 0; nt < 2; ++nt) acc2[mt][nt] = (floatx4){0.f, 0.f, 0.f, 0.f};

  short8 bcur2[2], bnext2[2];
  #pragma unroll
  for (int nt = 0; nt < 2; ++nt)
    bcur2[nt] = *(const short8*)(Btf2 + (((size_t)(w * 2 + nt) * 8 + 0) * 64 + l) * 8);

  #pragma unroll 1
  for (int step = 0; step < 8; ++step) {
    if (step < 7) {
      #pragma unroll
      for (int nt = 0; nt < 2; ++nt)
        bnext2[nt] = *(const short8*)(Btf2 + (((size_t)(w * 2 + nt) * 8 + step + 1) * 64 + l) * 8);
    }
    int ka = step * 64 + lhi * 16;
    short8 a[2];
    #pragma unroll
    for (int mt = 0; mt < 2; ++mt) {
      int r = mt * 16 + l15;
      a[mt] = *(const short8*)(As + r * 512 + (ka ^ ((r & 7) << 4)));
    }
    #pragma unroll
    for (int nt = 0; nt < 2; ++nt)
      #pragma unroll
      for (int mt = 0; mt < 2; ++mt)
        acc2[mt][nt] = __builtin_amdgcn_mfma_f32_16x16x32_bf16(a[mt], bcur2[nt], acc2[mt][nt], 0, 0, 0);
    if (step < 7) {
      #pragma unroll
      for (int nt = 0; nt < 2; ++nt) bcur2[nt] = bnext2[nt];
    }
  }

  #pragma unroll
  for (int mt = 0; mt < 2; ++mt)
    #pragma unroll
    for (int nt = 0; nt < 2; ++nt) {
      int col = w * 32 + nt * 16 + l15;
      #pragma unroll
      for (int j = 0; j < 4; ++j) {
        int rloc = mt * 16 + lhi * 4 + j;
        int row = row0 + rloc;
        if (row >= n) continue;
        float c = tanh_fast(acc2[mt][nt][j] + b2[col]);
        float uu = us[mt][nt][j];
        float hv = hf[(size_t)row * 128 + col];
        out[(size_t)row * 128 + col] = uu * hv + (1.f - uu) * c;
      }
    }
}

extern "C" void kernel_launch(void* const* d_in, const int* in_sizes, int n_in,
                              void* d_out, int out_size, void* d_ws, size_t ws_size,
                              hipStream_t stream) {
  const float* x     = (const float*)d_in[0];
  const void*  ei    = d_in[1];
  const float* h     = (const float*)d_in[3];
  const float* Wl    = (const float*)d_in[4];
  const float* Wr    = (const float*)d_in[5];
  const float* att   = (const float*)d_in[6];
  const float* bconv = (const float*)d_in[7];
  const float* W1    = (const float*)d_in[8];
  const float* b1    = (const float*)d_in[9];
  const float* W2    = (const float*)d_in[10];
  const float* b2    = (const float*)d_in[11];
  float* out = (float*)d_out;

  const int n = in_sizes[0] / 128;   // 50000
  const int E = in_sizes[1] / 2;     // 800000
  const int nbk = (n + 127) >> 7;    // 391

  char* w = (char*)d_ws;
  size_t o = 0;
  auto alloc = [&](size_t bytes) {
    char* p = w + o;
    o += bytes;
    o = (o + 255) & ~(size_t)255;
    return p;
  };
  int* flag         = (int*)alloc(4);
  int* bucketCnt    = (int*)alloc((size_t)nbk * 4);
  int* bucketBase   = (int*)alloc((size_t)(nbk + 1) * 4);
  int* bucketCursor = (int*)alloc((size_t)nbk * 4);
  int* off          = (int*)alloc((size_t)(n + 1) * 4);
  int* csr          = (int*)alloc((size_t)E * 4);
  unsigned long long* pairBuf = (unsigned long long*)alloc((size_t)E * 8);
  unsigned short* xl   = (unsigned short*)alloc((size_t)n * 128 * 2);
  unsigned short* xr   = (unsigned short*)alloc((size_t)n * 128 * 2);
  unsigned short* fbuf = (unsigned short*)alloc((size_t)n * 128 * 2);
  unsigned short* Btfxw = (unsigned short*)alloc(4096 * 8 * 2);
  unsigned short* Btf1  = (unsigned short*)alloc(8192 * 8 * 2);
  unsigned short* Btf2  = (unsigned short*)alloc(4096 * 8 * 2);

  hipMemsetAsync(bucketCnt, 0, (size_t)nbk * 4, stream);
  detect_kernel<<<1, 1024, 0, stream>>>((const unsigned int*)ei, 2LL * E, flag);
  bucket_hist<<<256, 256, 0, stream>>>(ei, E, flag, bucketCnt, nbk);
  bucket_scan<<<1, 64, 0, stream>>>(bucketCnt, bucketBase, bucketCursor, nbk);
  partition_kernel<<<(E + 4095) / 4096, 256, 0, stream>>>(ei, E, flag, bucketCursor,
                                                          pairBuf, nbk);
  csr_build<<<nbk, 256, 0, stream>>>(pairBuf, bucketBase, off, csr, n, E, nbk);
  wprep<<<64, 256, 0, stream>>>(Wl, Wr, W1, W2, Btfxw, Btf1, Btf2);

  int gblocks = (n + 31) / 32;
  gemm_xw<<<gblocks, 256, 0, stream>>>(x, Btfxw, xl, xr, n);
  node_kernel<<<(n + 3) / 4, 256, 0, stream>>>((const unsigned int*)xl, (const unsigned int*)xr,
                                               att, bconv, off, csr,
                                               (unsigned int*)fbuf, n);
  gemm_fused<<<gblocks, 256, 0, stream>>>(fbuf, h, Btf1, Btf2, b1, b2, out, n);
}

// Round 15
// 146.389 us; speedup vs baseline: 1.1063x; 1.1063x over previous
//
#include <hip/hip_runtime.h>
#include <hip/hip_bf16.h>
#include <math.h>

typedef __attribute__((ext_vector_type(8))) short short8;
typedef __attribute__((ext_vector_type(4))) float floatx4;

__device__ __forceinline__ unsigned short f2b(float f) {
  unsigned int u = __builtin_bit_cast(unsigned int, f);
  u += 0x7fffu + ((u >> 16) & 1u);
  return (unsigned short)(u >> 16);
}
__device__ __forceinline__ float b2f(unsigned short s) {
  unsigned int u = ((unsigned int)s) << 16;
  return __builtin_bit_cast(float, u);
}
__device__ __forceinline__ float blo(unsigned int u) {
  return __builtin_bit_cast(float, u << 16);
}
__device__ __forceinline__ float bhi(unsigned int u) {
  return __builtin_bit_cast(float, u & 0xffff0000u);
}
__device__ __forceinline__ float sigm(float v) { return 1.f / (1.f + __expf(-v)); }
__device__ __forceinline__ float tanh_fast(float y) {
  float t = __expf(2.f * y);
  return 1.f - 2.f / (t + 1.f);
}

// ---------------------------------------------------------------------------
// Block-local dtype probe: sample 64 odd u32 words spread across edge_index.
// int64 data (all indices < 2^32) -> all-zero; int32 -> some nonzero.
// Replaces the serial 1-block detect kernel.
// ---------------------------------------------------------------------------
__device__ __forceinline__ int probe_flag(const void* ei, int E) {
  __shared__ int fl;
  if (threadIdx.x == 0) fl = 0;
  __syncthreads();
  if (threadIdx.x < 64) {
    long long pos = (long long)threadIdx.x * (E / 64) + (E / 128);
    if (pos >= E) pos = E - 1;
    unsigned int v = ((const unsigned int*)ei)[2 * pos + 1];
    if (v != 0u) atomicOr(&fl, 1);
  }
  __syncthreads();
  return fl;   // 1 -> int32 data, 0 -> int64 data
}

__device__ __forceinline__ int load_dst(const void* ei, int E, int flag, int i) {
  if (flag == 0) return (int)((const long long*)ei)[(long long)E + i];
  return ((const int*)ei)[E + i];
}
__device__ __forceinline__ int load_src(const void* ei, int E, int flag, int i) {
  if (flag == 0) return (int)((const long long*)ei)[i];
  return ((const int*)ei)[i];
}

__global__ __launch_bounds__(256) void bucket_hist(const void* __restrict__ ei, int E,
                                                   int* __restrict__ bucketCnt, int nbk) {
  __shared__ int h[512];
  int fl = probe_flag(ei, E);
  for (int i = threadIdx.x; i < nbk; i += 256) h[i] = 0;
  __syncthreads();
  int gid = blockIdx.x * 256 + threadIdx.x;
  int stride = gridDim.x * 256;
  for (int i = gid; i < E; i += stride) {
    int d = load_dst(ei, E, fl, i);
    atomicAdd(&h[d >> 7], 1);
  }
  __syncthreads();
  for (int i = threadIdx.x; i < nbk; i += 256)
    if (h[i]) atomicAdd(&bucketCnt[i], h[i]);
}

__global__ __launch_bounds__(64) void bucket_scan(const int* __restrict__ bucketCnt,
                                                  int* __restrict__ bucketBase,
                                                  int* __restrict__ bucketCursor, int nbk) {
  int lane = threadIdx.x;
  int carry = 0;
  for (int base = 0; base < nbk; base += 64) {
    int i = base + lane;
    int v = (i < nbk) ? bucketCnt[i] : 0;
    int s = v;
    #pragma unroll
    for (int ofs = 1; ofs < 64; ofs <<= 1) {
      int t = __shfl_up(s, ofs, 64);
      if (lane >= ofs) s += t;
    }
    if (i < nbk) {
      int ex = s - v + carry;
      bucketBase[i] = ex;
      bucketCursor[i] = ex;
    }
    carry += __shfl(s, 63, 64);
  }
  if (lane == 0) bucketBase[nbk] = carry;   // == E
}

__global__ __launch_bounds__(256) void partition_kernel(const void* __restrict__ ei, int E,
                                                        int* __restrict__ bucketCursor,
                                                        unsigned long long* __restrict__ pairBuf,
                                                        int nbk) {
  __shared__ int h[512];
  __shared__ int base[512];
  int fl = probe_flag(ei, E);
  int tid = threadIdx.x;
  for (int i = tid; i < nbk; i += 256) h[i] = 0;
  __syncthreads();
  int tile0 = blockIdx.x * 4096;
  int sarr[16], darr[16], rank[16];
  #pragma unroll
  for (int k = 0; k < 16; ++k) {
    int idx = tile0 + tid + k * 256;
    rank[k] = -1;
    if (idx < E) {
      sarr[k] = load_src(ei, E, fl, idx);
      darr[k] = load_dst(ei, E, fl, idx);
      rank[k] = atomicAdd(&h[darr[k] >> 7], 1);
    }
  }
  __syncthreads();
  for (int i = tid; i < nbk; i += 256)
    base[i] = h[i] ? atomicAdd(&bucketCursor[i], h[i]) : 0;
  __syncthreads();
  #pragma unroll
  for (int k = 0; k < 16; ++k) {
    if (rank[k] >= 0) {
      int bk = darr[k] >> 7;
      pairBuf[(size_t)base[bk] + rank[k]] =
          ((unsigned long long)(unsigned)darr[k] << 32) | (unsigned)sarr[k];
    }
  }
}

__global__ __launch_bounds__(256) void csr_build(const unsigned long long* __restrict__ pairBuf,
                                                 const int* __restrict__ bucketBase,
                                                 int* __restrict__ off, int* __restrict__ csr,
                                                 int n, int E, int nbk) {
  __shared__ int cnt[128];
  __shared__ int start[128];
  __shared__ int wtot[4];
  int bk = blockIdx.x;
  int tid = threadIdx.x;
  int lo = bucketBase[bk], hi = bucketBase[bk + 1];
  int node0 = bk << 7;
  if (tid < 128) cnt[tid] = 0;
  __syncthreads();
  for (int i = lo + tid; i < hi; i += 256) {
    int d = (int)(pairBuf[i] >> 32);
    atomicAdd(&cnt[d - node0], 1);
  }
  __syncthreads();
  {
    int v = (tid < 128) ? cnt[tid] : 0;
    int s = v;
    #pragma unroll
    for (int ofs = 1; ofs < 64; ofs <<= 1) {
      int t = __shfl_up(s, ofs, 64);
      if ((tid & 63) >= ofs) s += t;
    }
    if ((tid & 63) == 63) wtot[tid >> 6] = s;
    __syncthreads();
    if (tid < 128) {
      int pre = (tid >> 6) ? wtot[0] : 0;
      start[tid] = s - v + pre;
    }
  }
  __syncthreads();
  int nNodes = n - node0;
  if (nNodes > 128) nNodes = 128;
  if (tid < nNodes) off[node0 + tid] = lo + start[tid];
  if (bk == nbk - 1 && tid == 0) off[n] = E;
  if (tid < 128) cnt[tid] = 0;
  __syncthreads();
  for (int i = lo + tid; i < hi; i += 256) {
    unsigned long long pr = pairBuf[i];
    int s = (int)(unsigned)pr;
    int ld = (int)(pr >> 32) - node0;
    int r = atomicAdd(&cnt[ld], 1);
    csr[lo + start[ld] + r] = s;
  }
}

// ---------------------------------------------------------------------------
// Weights -> bf16 in MFMA FRAGMENT ORDER.
// ---------------------------------------------------------------------------
__global__ __launch_bounds__(256) void wprep(const float* __restrict__ Wl,
                                             const float* __restrict__ Wr,
                                             const float* __restrict__ W1,
                                             const float* __restrict__ W2,
                                             unsigned short* __restrict__ Btfxw,
                                             unsigned short* __restrict__ Btf1,
                                             unsigned short* __restrict__ Btf2) {
  int gid = blockIdx.x * 256 + threadIdx.x;   // 16384 total
  if (gid < 4096) {                           // xw
    int lane = gid & 63, fid = gid >> 6;
    int l15 = lane & 15, lhi = lane >> 4;
    int kk = fid & 3, nt = (fid >> 2) & 3, w = fid >> 4;
    int col = w * 64 + nt * 16 + l15;
    int k0 = kk * 32 + lhi * 8;
    #pragma unroll
    for (int e = 0; e < 8; ++e) {
      float v = (col < 128) ? Wl[(k0 + e) * 128 + col] : Wr[(k0 + e) * 128 + (col - 128)];
      Btfxw[(size_t)gid * 8 + e] = f2b(v);
    }
  } else if (gid < 12288) {                   // W1
    int g = gid - 4096;
    int lane = g & 63, fid = g >> 6;
    int l15 = lane & 15, lhi = lane >> 4;
    int kk = fid & 1, ks = (fid >> 1) & 3, nt = (fid >> 3) & 3, w = fid >> 5;
    int col = (nt < 2) ? (w * 32 + nt * 16 + l15) : (128 + w * 32 + (nt - 2) * 16 + l15);
    int k0 = ks * 64 + kk * 32 + lhi * 8;
    #pragma unroll
    for (int e = 0; e < 8; ++e)
      Btf1[(size_t)g * 8 + e] = f2b(W1[(k0 + e) * 256 + col]);
  } else {                                    // W2
    int g = gid - 12288;
    int lane = g & 63, fid = g >> 6;
    int l15 = lane & 15, lhi = lane >> 4;
    int kk = fid & 1, ks = (fid >> 1) & 3, nt = (fid >> 3) & 1, w = fid >> 4;
    int col = w * 32 + nt * 16 + l15;
    int k0 = ks * 64 + kk * 32 + lhi * 8;
    #pragma unroll
    for (int e = 0; e < 8; ++e)
      Btf2[(size_t)g * 8 + e] = f2b(W2[(k0 + e) * 128 + col]);
  }
}

// ---------------------------------------------------------------------------
// xl|xr = x @ [Wl|Wr].  BM=32, LDS = A only (8 KB).  B fragments from L2
// with one-step register double-buffer (bcur/bnext).
// ---------------------------------------------------------------------------
__global__ __launch_bounds__(256) void gemm_xw(const float* __restrict__ x,
                                               const unsigned short* __restrict__ Btf,
                                               unsigned short* __restrict__ xl,
                                               unsigned short* __restrict__ xr, int n) {
  __shared__ char As[32 * 256];    // 32 rows x 128 bf16, swizzled
  int t = threadIdx.x;
  int w = t >> 6, l = t & 63;
  int row0 = blockIdx.x * 32;
  int l15 = l & 15, lhi = l >> 4;

  // stage A from f32: src linear, dest swizzled (rule #21)
  #pragma unroll
  for (int u_ = 0; u_ < 2; ++u_) {
    int unit = t + u_ * 256;
    int r = unit >> 4, slot = unit & 15;
    int grow = row0 + r;
    uint4 o = make_uint4(0, 0, 0, 0);
    if (grow < n) {
      const float* s = x + (size_t)grow * 128 + slot * 8;
      float4 f0 = *(const float4*)s, f1 = *(const float4*)(s + 4);
      o.x = (unsigned)f2b(f0.x) | ((unsigned)f2b(f0.y) << 16);
      o.y = (unsigned)f2b(f0.z) | ((unsigned)f2b(f0.w) << 16);
      o.z = (unsigned)f2b(f1.x) | ((unsigned)f2b(f1.y) << 16);
      o.w = (unsigned)f2b(f1.z) | ((unsigned)f2b(f1.w) << 16);
    }
    *(uint4*)(As + r * 256 + ((slot * 16) ^ ((r & 7) << 4))) = o;
  }
  __syncthreads();

  floatx4 acc[2][4];
  #pragma unroll
  for (int mt = 0; mt < 2; ++mt)
    #pragma unroll
    for (int nt = 0; nt < 4; ++nt) acc[mt][nt] = (floatx4){0.f, 0.f, 0.f, 0.f};

  short8 bcur[4], bnext[4];
  #pragma unroll
  for (int nt = 0; nt < 4; ++nt)
    bcur[nt] = *(const short8*)(Btf + (((size_t)(w * 4 + nt) * 4 + 0) * 64 + l) * 8);

  #pragma unroll 1
  for (int kk = 0; kk < 4; ++kk) {
    if (kk < 3) {
      #pragma unroll
      for (int nt = 0; nt < 4; ++nt)
        bnext[nt] = *(const short8*)(Btf + (((size_t)(w * 4 + nt) * 4 + kk + 1) * 64 + l) * 8);
    }
    int ko = kk * 64 + lhi * 16;
    short8 a[2];
    #pragma unroll
    for (int mt = 0; mt < 2; ++mt) {
      int r = mt * 16 + l15;
      a[mt] = *(const short8*)(As + r * 256 + (ko ^ ((r & 7) << 4)));
    }
    #pragma unroll
    for (int nt = 0; nt < 4; ++nt)
      #pragma unroll
      for (int mt = 0; mt < 2; ++mt)
        acc[mt][nt] = __builtin_amdgcn_mfma_f32_16x16x32_bf16(a[mt], bcur[nt], acc[mt][nt], 0, 0, 0);
    if (kk < 3) {
      #pragma unroll
      for (int nt = 0; nt < 4; ++nt) bcur[nt] = bnext[nt];
    }
  }

  #pragma unroll
  for (int mt = 0; mt < 2; ++mt)
    #pragma unroll
    for (int nt = 0; nt < 4; ++nt) {
      int col = w * 64 + nt * 16 + l15;
      int rbase = row0 + mt * 16 + lhi * 4;
      #pragma unroll
      for (int j = 0; j < 4; ++j) {
        int row = rbase + j;
        if (row >= n) continue;
        unsigned short v = f2b(acc[mt][nt][j]);
        if (col < 128) xl[(size_t)row * 128 + col] = v;
        else           xr[(size_t)row * 128 + (col - 128)] = v;
      }
    }
}

// ---------------------------------------------------------------------------
// Node pass (PROVEN 47.6 us config, r11/r12 bench): one wave per node;
// 2 edges/pass; lane&31 owns dims 4hl..4hl+3; head reduce = shfl 1,2,4;
// att pre-scaled by log2(e) -> exp2; 32-bit gather offsets; 28 VGPR.
// Latency hidden by TLP (occupancy ~64%) — do NOT add register batching
// (r13/r14: +VGPR -> -occupancy -> slower).
// ---------------------------------------------------------------------------
__global__ __launch_bounds__(256) void node_kernel(const unsigned int* __restrict__ xl32,
                                                   const unsigned int* __restrict__ xr32,
                                                   const float* __restrict__ att,
                                                   const float* __restrict__ bias,
                                                   const int* __restrict__ off,
                                                   const int* __restrict__ csr,
                                                   unsigned int* __restrict__ fout, int n) {
  int wid = threadIdx.x >> 6, lane = threadIdx.x & 63;
  int node = blockIdx.x * 4 + wid;
  if (node >= n) return;
  int hl = lane & 31;
  bool upper = lane >= 32;
  const float LOG2E = 1.44269504f;
  float4 av = *(const float4*)(att + hl * 4);
  float a0 = av.x * LOG2E, a1 = av.y * LOG2E, a2 = av.z * LOG2E, a3 = av.w * LOG2E;
  uint2 xrp = *(const uint2*)(xr32 + node * 64 + hl * 2);
  float xr0 = blo(xrp.x), xr1 = bhi(xrp.x);
  float xr2 = blo(xrp.y), xr3 = bhi(xrp.y);
  float num0 = 0.f, num1 = 0.f, num2 = 0.f, num3 = 0.f, den = 0.f;
  int beg = off[node], end = off[node + 1];

  auto edge2 = [&](int sLo, int sHi, bool hiValid) {
    int s = upper ? sHi : sLo;
    uint2 g = *(const uint2*)(xl32 + ((unsigned)s << 6) + (unsigned)(hl << 1));
    float x0 = blo(g.x), x1 = bhi(g.x), x2 = blo(g.y), x3 = bhi(g.y);
    float m0 = x0 + xr0, m1 = x1 + xr1, m2 = x2 + xr2, m3 = x3 + xr3;
    float l0 = fmaxf(m0, 0.2f * m0), l1 = fmaxf(m1, 0.2f * m1);
    float l2 = fmaxf(m2, 0.2f * m2), l3 = fmaxf(m3, 0.2f * m3);
    float p = l0 * a0;
    p = fmaf(l1, a1, p);
    p = fmaf(l2, a2, p);
    p = fmaf(l3, a3, p);
    p += __shfl_xor(p, 1, 64);
    p += __shfl_xor(p, 2, 64);
    p += __shfl_xor(p, 4, 64);
    float wgt = __builtin_amdgcn_exp2f(p);
    if (upper && !hiValid) wgt = 0.f;
    num0 = fmaf(wgt, x0, num0);
    num1 = fmaf(wgt, x1, num1);
    num2 = fmaf(wgt, x2, num2);
    num3 = fmaf(wgt, x3, num3);
    den += wgt;
  };

  if (beg < end) {
    edge2(node, csr[beg], true);          // self loop paired with first edge
    for (int base = beg + 1; base < end; base += 64) {
      int cnt = end - base;
      if (cnt > 64) cnt = 64;
      int my = csr[base + (lane < cnt ? lane : 0)];
      int i = 0;
      for (; i + 4 <= cnt; i += 4) {
        int sa = __builtin_amdgcn_readlane(my, i);
        int sb = __builtin_amdgcn_readlane(my, i + 1);
        int sc = __builtin_amdgcn_readlane(my, i + 2);
        int sd = __builtin_amdgcn_readlane(my, i + 3);
        edge2(sa, sb, true);
        edge2(sc, sd, true);
      }
      for (; i + 2 <= cnt; i += 2) {
        int sa = __builtin_amdgcn_readlane(my, i);
        int sb = __builtin_amdgcn_readlane(my, i + 1);
        edge2(sa, sb, true);
      }
      if (i < cnt) edge2(__builtin_amdgcn_readlane(my, i), node, false);
    }
  } else {
    edge2(node, node, false);             // isolated node: self loop only
  }

  num0 += __shfl_xor(num0, 32, 64);
  num1 += __shfl_xor(num1, 32, 64);
  num2 += __shfl_xor(num2, 32, 64);
  num3 += __shfl_xor(num3, 32, 64);
  den  += __shfl_xor(den, 32, 64);

  if (!upper) {
    float inv = 1.f / (den + 1e-16f);
    float4 bv = *(const float4*)(bias + hl * 4);
    float v0 = num0 * inv + bv.x;
    float v1 = num1 * inv + bv.y;
    float v2 = num2 * inv + bv.z;
    float v3 = num3 * inv + bv.w;
    uint2 o;
    o.x = (unsigned)f2b(sigm(v0)) | ((unsigned)f2b(sigm(v1)) << 16);
    o.y = (unsigned)f2b(sigm(v2)) | ((unsigned)f2b(sigm(v3)) << 16);
    *(uint2*)(fout + node * 64 + hl * 2) = o;
  }
}

// ---------------------------------------------------------------------------
// Fused GRU GEMMs.  BM=32, LDS = A only (16 KB), 1563 blocks.
// B fragments from L2 with one-step register double-buffer.
// Phase1 wave w: cols {w*32..} U {128+w*32..} -> u gate stays in registers.
// ---------------------------------------------------------------------------
__global__ __launch_bounds__(256) void gemm_fused(const unsigned short* __restrict__ fbuf,
                                                  const float* __restrict__ hf,
                                                  const unsigned short* __restrict__ Btf1,
                                                  const unsigned short* __restrict__ Btf2,
                                                  const float* __restrict__ b1,
                                                  const float* __restrict__ b2,
                                                  float* __restrict__ out, int n) {
  __shared__ char As[32 * 512];           // [f|h] 32 rows x 256 bf16, swizzled
  int t = threadIdx.x;
  int w = t >> 6, l = t & 63;
  int row0 = blockIdx.x * 32;
  int l15 = l & 15, lhi = l >> 4;

  // stage A = [f | h]: src linear, dest swizzled
  #pragma unroll
  for (int u_ = 0; u_ < 4; ++u_) {
    int unit = t + u_ * 256;
    int r = unit >> 5, slot = unit & 31;
    int koff = slot * 16;
    int grow = row0 + r;
    uint4 v = make_uint4(0, 0, 0, 0);
    if (grow < n) {
      if (koff < 256) {
        v = *(const uint4*)(fbuf + (size_t)grow * 128 + koff / 2);
      } else {
        const float* s = hf + (size_t)grow * 128 + (koff - 256) / 2;
        float4 f0 = *(const float4*)s, f1 = *(const float4*)(s + 4);
        v.x = (unsigned)f2b(f0.x) | ((unsigned)f2b(f0.y) << 16);
        v.y = (unsigned)f2b(f0.z) | ((unsigned)f2b(f0.w) << 16);
        v.z = (unsigned)f2b(f1.x) | ((unsigned)f2b(f1.y) << 16);
        v.w = (unsigned)f2b(f1.z) | ((unsigned)f2b(f1.w) << 16);
      }
    }
    *(uint4*)(As + r * 512 + (koff ^ ((r & 7) << 4))) = v;
  }
  __syncthreads();

  // ---- phase 1: K=256, N=256; 8 steps of K=32 ----
  floatx4 acc[2][4];
  #pragma unroll
  for (int mt = 0; mt < 2; ++mt)
    #pragma unroll
    for (int nt = 0; nt < 4; ++nt) acc[mt][nt] = (floatx4){0.f, 0.f, 0.f, 0.f};

  short8 bcur[4], bnext[4];
  #pragma unroll
  for (int nt = 0; nt < 4; ++nt)
    bcur[nt] = *(const short8*)(Btf1 + (((size_t)(w * 4 + nt) * 8 + 0) * 64 + l) * 8);

  #pragma unroll 1
  for (int step = 0; step < 8; ++step) {
    if (step < 7) {
      #pragma unroll
      for (int nt = 0; nt < 4; ++nt)
        bnext[nt] = *(const short8*)(Btf1 + (((size_t)(w * 4 + nt) * 8 + step + 1) * 64 + l) * 8);
    }
    int ka = step * 64 + lhi * 16;
    short8 a[2];
    #pragma unroll
    for (int mt = 0; mt < 2; ++mt) {
      int r = mt * 16 + l15;
      a[mt] = *(const short8*)(As + r * 512 + (ka ^ ((r & 7) << 4)));
    }
    #pragma unroll
    for (int nt = 0; nt < 4; ++nt)
      #pragma unroll
      for (int mt = 0; mt < 2; ++mt)
        acc[mt][nt] = __builtin_amdgcn_mfma_f32_16x16x32_bf16(a[mt], bcur[nt], acc[mt][nt], 0, 0, 0);
    if (step < 7) {
      #pragma unroll
      for (int nt = 0; nt < 4; ++nt) bcur[nt] = bnext[nt];
    }
  }
  __syncthreads();   // all waves done reading As (h half) before overwrite

  // phase-1 epilogue: r-cols -> rh overwrites h half of As (swizzled);
  // u-cols stay in registers (layout matches phase-2 accumulator).
  float us[2][2][4];
  #pragma unroll
  for (int mt = 0; mt < 2; ++mt)
    #pragma unroll
    for (int nt = 0; nt < 4; ++nt) {
      #pragma unroll
      for (int j = 0; j < 4; ++j) {
        int rloc = mt * 16 + lhi * 4 + j;
        if (nt < 2) {
          int col = w * 32 + nt * 16 + l15;
          float s = sigm(acc[mt][nt][j] + b1[col]);
          int byteoff = (256 + col * 2) ^ ((rloc & 7) << 4);
          char* p = As + rloc * 512 + byteoff;
          unsigned short hv = *(unsigned short*)p;
          *(unsigned short*)p = f2b(s * b2f(hv));
        } else {
          int col = 128 + w * 32 + (nt - 2) * 16 + l15;
          us[mt][nt - 2][j] = sigm(acc[mt][nt][j] + b1[col]);
        }
      }
    }
  __syncthreads();

  // ---- phase 2: K=256, N=128; wave w owns cols w*32..+31 ----
  floatx4 acc2[2][2];
  #pragma unroll
  for (int mt = 0; mt < 2; ++mt)
    #pragma unroll
    for (int nt = 0; nt < 2; ++nt) acc2[mt][nt] = (floatx4){0.f, 0.f, 0.f, 0.f};

  short8 bcur2[2], bnext2[2];
  #pragma unroll
  for (int nt = 0; nt < 2; ++nt)
    bcur2[nt] = *(const short8*)(Btf2 + (((size_t)(w * 2 + nt) * 8 + 0) * 64 + l) * 8);

  #pragma unroll 1
  for (int step = 0; step < 8; ++step) {
    if (step < 7) {
      #pragma unroll
      for (int nt = 0; nt < 2; ++nt)
        bnext2[nt] = *(const short8*)(Btf2 + (((size_t)(w * 2 + nt) * 8 + step + 1) * 64 + l) * 8);
    }
    int ka = step * 64 + lhi * 16;
    short8 a[2];
    #pragma unroll
    for (int mt = 0; mt < 2; ++mt) {
      int r = mt * 16 + l15;
      a[mt] = *(const short8*)(As + r * 512 + (ka ^ ((r & 7) << 4)));
    }
    #pragma unroll
    for (int nt = 0; nt < 2; ++nt)
      #pragma unroll
      for (int mt = 0; mt < 2; ++mt)
        acc2[mt][nt] = __builtin_amdgcn_mfma_f32_16x16x32_bf16(a[mt], bcur2[nt], acc2[mt][nt], 0, 0, 0);
    if (step < 7) {
      #pragma unroll
      for (int nt = 0; nt < 2; ++nt) bcur2[nt] = bnext2[nt];
    }
  }

  #pragma unroll
  for (int mt = 0; mt < 2; ++mt)
    #pragma unroll
    for (int nt = 0; nt < 2; ++nt) {
      int col = w * 32 + nt * 16 + l15;
      #pragma unroll
      for (int j = 0; j < 4; ++j) {
        int rloc = mt * 16 + lhi * 4 + j;
        int row = row0 + rloc;
        if (row >= n) continue;
        float c = tanh_fast(acc2[mt][nt][j] + b2[col]);
        float uu = us[mt][nt][j];
        float hv = hf[(size_t)row * 128 + col];
        out[(size_t)row * 128 + col] = uu * hv + (1.f - uu) * c;
      }
    }
}

extern "C" void kernel_launch(void* const* d_in, const int* in_sizes, int n_in,
                              void* d_out, int out_size, void* d_ws, size_t ws_size,
                              hipStream_t stream) {
  const float* x     = (const float*)d_in[0];
  const void*  ei    = d_in[1];
  const float* h     = (const float*)d_in[3];
  const float* Wl    = (const float*)d_in[4];
  const float* Wr    = (const float*)d_in[5];
  const float* att   = (const float*)d_in[6];
  const float* bconv = (const float*)d_in[7];
  const float* W1    = (const float*)d_in[8];
  const float* b1    = (const float*)d_in[9];
  const float* W2    = (const float*)d_in[10];
  const float* b2    = (const float*)d_in[11];
  float* out = (float*)d_out;

  const int n = in_sizes[0] / 128;   // 50000
  const int E = in_sizes[1] / 2;     // 800000
  const int nbk = (n + 127) >> 7;    // 391

  char* w = (char*)d_ws;
  size_t o = 0;
  auto alloc = [&](size_t bytes) {
    char* p = w + o;
    o += bytes;
    o = (o + 255) & ~(size_t)255;
    return p;
  };
  int* bucketCnt    = (int*)alloc((size_t)nbk * 4);
  int* bucketBase   = (int*)alloc((size_t)(nbk + 1) * 4);
  int* bucketCursor = (int*)alloc((size_t)nbk * 4);
  int* off          = (int*)alloc((size_t)(n + 1) * 4);
  int* csr          = (int*)alloc((size_t)E * 4);
  unsigned long long* pairBuf = (unsigned long long*)alloc((size_t)E * 8);
  unsigned short* xl   = (unsigned short*)alloc((size_t)n * 128 * 2);
  unsigned short* xr   = (unsigned short*)alloc((size_t)n * 128 * 2);
  unsigned short* fbuf = (unsigned short*)alloc((size_t)n * 128 * 2);
  unsigned short* Btfxw = (unsigned short*)alloc(4096 * 8 * 2);
  unsigned short* Btf1  = (unsigned short*)alloc(8192 * 8 * 2);
  unsigned short* Btf2  = (unsigned short*)alloc(4096 * 8 * 2);

  hipMemsetAsync(bucketCnt, 0, (size_t)nbk * 4, stream);
  bucket_hist<<<256, 256, 0, stream>>>(ei, E, bucketCnt, nbk);
  bucket_scan<<<1, 64, 0, stream>>>(bucketCnt, bucketBase, bucketCursor, nbk);
  partition_kernel<<<(E + 4095) / 4096, 256, 0, stream>>>(ei, E, bucketCursor, pairBuf, nbk);
  csr_build<<<nbk, 256, 0, stream>>>(pairBuf, bucketBase, off, csr, n, E, nbk);
  wprep<<<64, 256, 0, stream>>>(Wl, Wr, W1, W2, Btfxw, Btf1, Btf2);

  int gblocks = (n + 31) / 32;
  gemm_xw<<<gblocks, 256, 0, stream>>>(x, Btfxw, xl, xr, n);
  node_kernel<<<(n + 3) / 4, 256, 0, stream>>>((const unsigned int*)xl, (const unsigned int*)xr,
                                               att, bconv, off, csr,
                                               (unsigned int*)fbuf, n);
  gemm_fused<<<gblocks, 256, 0, stream>>>(fbuf, h, Btf1, Btf2, b1, b2, out, n);
}

// Round 16
// 136.029 us; speedup vs baseline: 1.1906x; 1.0762x over previous
//
#include <hip/hip_runtime.h>
#include <hip/hip_bf16.h>
#include <math.h>

typedef __attribute__((ext_vector_type(8))) short short8;
typedef __attribute__((ext_vector_type(4))) float floatx4;

__device__ __forceinline__ unsigned short f2b(float f) {
  unsigned int u = __builtin_bit_cast(unsigned int, f);
  u += 0x7fffu + ((u >> 16) & 1u);
  return (unsigned short)(u >> 16);
}
__device__ __forceinline__ float b2f(unsigned short s) {
  unsigned int u = ((unsigned int)s) << 16;
  return __builtin_bit_cast(float, u);
}
__device__ __forceinline__ float blo(unsigned int u) {
  return __builtin_bit_cast(float, u << 16);
}
__device__ __forceinline__ float bhi(unsigned int u) {
  return __builtin_bit_cast(float, u & 0xffff0000u);
}
__device__ __forceinline__ float sigm(float v) { return 1.f / (1.f + __expf(-v)); }
__device__ __forceinline__ float tanh_fast(float y) {
  float t = __expf(2.f * y);
  return 1.f - 2.f / (t + 1.f);
}

// ---------------------------------------------------------------------------
// Block-local dtype probe: sample 64 odd u32 words spread across edge_index.
// int64 data (indices < 2^32) -> all-zero; int32 -> some nonzero.
// ---------------------------------------------------------------------------
__device__ __forceinline__ int probe_flag(const void* ei, int E) {
  __shared__ int fl;
  if (threadIdx.x == 0) fl = 0;
  __syncthreads();
  if (threadIdx.x < 64) {
    long long pos = (long long)threadIdx.x * (E / 64) + (E / 128);
    if (pos >= E) pos = E - 1;
    unsigned int v = ((const unsigned int*)ei)[2 * pos + 1];
    if (v != 0u) atomicOr(&fl, 1);
  }
  __syncthreads();
  return fl;   // 1 -> int32 data, 0 -> int64 data
}

__device__ __forceinline__ int load_dst(const void* ei, int E, int flag, int i) {
  if (flag == 0) return (int)((const long long*)ei)[(long long)E + i];
  return ((const int*)ei)[E + i];
}
__device__ __forceinline__ int load_src(const void* ei, int E, int flag, int i) {
  if (flag == 0) return (int)((const long long*)ei)[i];
  return ((const int*)ei)[i];
}

// ---------------------------------------------------------------------------
// K1 (grid-fused): blocks [0,256) = bucket histogram; [256,320) = weight prep.
// Independent entry nodes of the dependency graph — no ordering needed.
// ---------------------------------------------------------------------------
__global__ __launch_bounds__(256) void prep1(const void* __restrict__ ei, int E,
                                             int* __restrict__ bucketCnt, int nbk,
                                             const float* __restrict__ Wl,
                                             const float* __restrict__ Wr,
                                             const float* __restrict__ W1,
                                             const float* __restrict__ W2,
                                             unsigned short* __restrict__ Btfxw,
                                             unsigned short* __restrict__ Btf1,
                                             unsigned short* __restrict__ Btf2) {
  __shared__ int h[512];
  if (blockIdx.x < 256) {              // ---- bucket_hist ----
    int fl = probe_flag(ei, E);
    for (int i = threadIdx.x; i < nbk; i += 256) h[i] = 0;
    __syncthreads();
    int gid = blockIdx.x * 256 + threadIdx.x;
    int stride = 256 * 256;
    for (int i = gid; i < E; i += stride) {
      int d = load_dst(ei, E, fl, i);
      atomicAdd(&h[d >> 7], 1);
    }
    __syncthreads();
    for (int i = threadIdx.x; i < nbk; i += 256)
      if (h[i]) atomicAdd(&bucketCnt[i], h[i]);
  } else {                             // ---- wprep ----
    int gid = (blockIdx.x - 256) * 256 + threadIdx.x;   // 16384 total
    if (gid < 4096) {                  // xw
      int lane = gid & 63, fid = gid >> 6;
      int l15 = lane & 15, lhi = lane >> 4;
      int kk = fid & 3, nt = (fid >> 2) & 3, w = fid >> 4;
      int col = w * 64 + nt * 16 + l15;
      int k0 = kk * 32 + lhi * 8;
      #pragma unroll
      for (int e = 0; e < 8; ++e) {
        float v = (col < 128) ? Wl[(k0 + e) * 128 + col] : Wr[(k0 + e) * 128 + (col - 128)];
        Btfxw[(size_t)gid * 8 + e] = f2b(v);
      }
    } else if (gid < 12288) {          // W1
      int g = gid - 4096;
      int lane = g & 63, fid = g >> 6;
      int l15 = lane & 15, lhi = lane >> 4;
      int kk = fid & 1, ks = (fid >> 1) & 3, nt = (fid >> 3) & 3, w = fid >> 5;
      int col = (nt < 2) ? (w * 32 + nt * 16 + l15) : (128 + w * 32 + (nt - 2) * 16 + l15);
      int k0 = ks * 64 + kk * 32 + lhi * 8;
      #pragma unroll
      for (int e = 0; e < 8; ++e)
        Btf1[(size_t)g * 8 + e] = f2b(W1[(k0 + e) * 256 + col]);
    } else {                           // W2
      int g = gid - 12288;
      int lane = g & 63, fid = g >> 6;
      int l15 = lane & 15, lhi = lane >> 4;
      int kk = fid & 1, ks = (fid >> 1) & 3, nt = (fid >> 3) & 1, w = fid >> 4;
      int col = w * 32 + nt * 16 + l15;
      int k0 = ks * 64 + kk * 32 + lhi * 8;
      #pragma unroll
      for (int e = 0; e < 8; ++e)
        Btf2[(size_t)g * 8 + e] = f2b(W2[(k0 + e) * 128 + col]);
    }
  }
}

__global__ __launch_bounds__(64) void bucket_scan(const int* __restrict__ bucketCnt,
                                                  int* __restrict__ bucketBase,
                                                  int* __restrict__ bucketCursor, int nbk) {
  int lane = threadIdx.x;
  int carry = 0;
  for (int base = 0; base < nbk; base += 64) {
    int i = base + lane;
    int v = (i < nbk) ? bucketCnt[i] : 0;
    int s = v;
    #pragma unroll
    for (int ofs = 1; ofs < 64; ofs <<= 1) {
      int t = __shfl_up(s, ofs, 64);
      if (lane >= ofs) s += t;
    }
    if (i < nbk) {
      int ex = s - v + carry;
      bucketBase[i] = ex;
      bucketCursor[i] = ex;
    }
    carry += __shfl(s, 63, 64);
  }
  if (lane == 0) bucketBase[nbk] = carry;   // == E
}

__global__ __launch_bounds__(256) void partition_kernel(const void* __restrict__ ei, int E,
                                                        int* __restrict__ bucketCursor,
                                                        unsigned long long* __restrict__ pairBuf,
                                                        int nbk) {
  __shared__ int h[512];
  __shared__ int base[512];
  int fl = probe_flag(ei, E);
  int tid = threadIdx.x;
  for (int i = tid; i < nbk; i += 256) h[i] = 0;
  __syncthreads();
  int tile0 = blockIdx.x * 4096;
  int sarr[16], darr[16], rank[16];
  #pragma unroll
  for (int k = 0; k < 16; ++k) {
    int idx = tile0 + tid + k * 256;
    rank[k] = -1;
    if (idx < E) {
      sarr[k] = load_src(ei, E, fl, idx);
      darr[k] = load_dst(ei, E, fl, idx);
      rank[k] = atomicAdd(&h[darr[k] >> 7], 1);
    }
  }
  __syncthreads();
  for (int i = tid; i < nbk; i += 256)
    base[i] = h[i] ? atomicAdd(&bucketCursor[i], h[i]) : 0;
  __syncthreads();
  #pragma unroll
  for (int k = 0; k < 16; ++k) {
    if (rank[k] >= 0) {
      int bk = darr[k] >> 7;
      pairBuf[(size_t)base[bk] + rank[k]] =
          ((unsigned long long)(unsigned)darr[k] << 32) | (unsigned)sarr[k];
    }
  }
}

// ---------------------------------------------------------------------------
// K4 (grid-fused): blocks [0,nbk) = csr_build; [nbk, nbk+1563) = gemm_xw.
// Both feed node_kernel, which needs csr AND xl/xr — no false dependency.
// ---------------------------------------------------------------------------
__global__ __launch_bounds__(256) void csr_xw(const unsigned long long* __restrict__ pairBuf,
                                              const int* __restrict__ bucketBase,
                                              int* __restrict__ off, int* __restrict__ csr,
                                              int n, int E, int nbk,
                                              const float* __restrict__ x,
                                              const unsigned short* __restrict__ Btf,
                                              unsigned short* __restrict__ xl,
                                              unsigned short* __restrict__ xr) {
  __shared__ char As[32 * 256];   // gemm_xw A tile (csr branch leaves unused)
  __shared__ int cnt[128];
  __shared__ int start[128];
  __shared__ int wtot[4];
  int tid = threadIdx.x;

  if (blockIdx.x < (unsigned)nbk) {   // ---- csr_build ----
    int bk = blockIdx.x;
    int lo = bucketBase[bk], hi = bucketBase[bk + 1];
    int node0 = bk << 7;
    if (tid < 128) cnt[tid] = 0;
    __syncthreads();
    for (int i = lo + tid; i < hi; i += 256) {
      int d = (int)(pairBuf[i] >> 32);
      atomicAdd(&cnt[d - node0], 1);
    }
    __syncthreads();
    {
      int v = (tid < 128) ? cnt[tid] : 0;
      int s = v;
      #pragma unroll
      for (int ofs = 1; ofs < 64; ofs <<= 1) {
        int t = __shfl_up(s, ofs, 64);
        if ((tid & 63) >= ofs) s += t;
      }
      if ((tid & 63) == 63) wtot[tid >> 6] = s;
      __syncthreads();
      if (tid < 128) {
        int pre = (tid >> 6) ? wtot[0] : 0;
        start[tid] = s - v + pre;
      }
    }
    __syncthreads();
    int nNodes = n - node0;
    if (nNodes > 128) nNodes = 128;
    if (tid < nNodes) off[node0 + tid] = lo + start[tid];
    if (bk == nbk - 1 && tid == 0) off[n] = E;
    if (tid < 128) cnt[tid] = 0;
    __syncthreads();
    for (int i = lo + tid; i < hi; i += 256) {
      unsigned long long pr = pairBuf[i];
      int s = (int)(unsigned)pr;
      int ld = (int)(pr >> 32) - node0;
      int r = atomicAdd(&cnt[ld], 1);
      csr[lo + start[ld] + r] = s;
    }
    return;
  }

  // ---- gemm_xw: xl|xr = x @ [Wl|Wr].  BM=32; B frags from L2 dbuf ----
  int bid = blockIdx.x - nbk;
  int w = tid >> 6, l = tid & 63;
  int row0 = bid * 32;
  int l15 = l & 15, lhi = l >> 4;

  #pragma unroll
  for (int u_ = 0; u_ < 2; ++u_) {
    int unit = tid + u_ * 256;
    int r = unit >> 4, slot = unit & 15;
    int grow = row0 + r;
    uint4 o = make_uint4(0, 0, 0, 0);
    if (grow < n) {
      const float* s = x + (size_t)grow * 128 + slot * 8;
      float4 f0 = *(const float4*)s, f1 = *(const float4*)(s + 4);
      o.x = (unsigned)f2b(f0.x) | ((unsigned)f2b(f0.y) << 16);
      o.y = (unsigned)f2b(f0.z) | ((unsigned)f2b(f0.w) << 16);
      o.z = (unsigned)f2b(f1.x) | ((unsigned)f2b(f1.y) << 16);
      o.w = (unsigned)f2b(f1.z) | ((unsigned)f2b(f1.w) << 16);
    }
    *(uint4*)(As + r * 256 + ((slot * 16) ^ ((r & 7) << 4))) = o;
  }
  __syncthreads();

  floatx4 acc[2][4];
  #pragma unroll
  for (int mt = 0; mt < 2; ++mt)
    #pragma unroll
    for (int nt = 0; nt < 4; ++nt) acc[mt][nt] = (floatx4){0.f, 0.f, 0.f, 0.f};

  short8 bcur[4], bnext[4];
  #pragma unroll
  for (int nt = 0; nt < 4; ++nt)
    bcur[nt] = *(const short8*)(Btf + (((size_t)(w * 4 + nt) * 4 + 0) * 64 + l) * 8);

  #pragma unroll 1
  for (int kk = 0; kk < 4; ++kk) {
    if (kk < 3) {
      #pragma unroll
      for (int nt = 0; nt < 4; ++nt)
        bnext[nt] = *(const short8*)(Btf + (((size_t)(w * 4 + nt) * 4 + kk + 1) * 64 + l) * 8);
    }
    int ko = kk * 64 + lhi * 16;
    short8 a[2];
    #pragma unroll
    for (int mt = 0; mt < 2; ++mt) {
      int r = mt * 16 + l15;
      a[mt] = *(const short8*)(As + r * 256 + (ko ^ ((r & 7) << 4)));
    }
    #pragma unroll
    for (int nt = 0; nt < 4; ++nt)
      #pragma unroll
      for (int mt = 0; mt < 2; ++mt)
        acc[mt][nt] = __builtin_amdgcn_mfma_f32_16x16x32_bf16(a[mt], bcur[nt], acc[mt][nt], 0, 0, 0);
    if (kk < 3) {
      #pragma unroll
      for (int nt = 0; nt < 4; ++nt) bcur[nt] = bnext[nt];
    }
  }

  #pragma unroll
  for (int mt = 0; mt < 2; ++mt)
    #pragma unroll
    for (int nt = 0; nt < 4; ++nt) {
      int col = w * 64 + nt * 16 + l15;
      int rbase = row0 + mt * 16 + lhi * 4;
      #pragma unroll
      for (int j = 0; j < 4; ++j) {
        int row = rbase + j;
        if (row >= n) continue;
        unsigned short v = f2b(acc[mt][nt][j]);
        if (col < 128) xl[(size_t)row * 128 + col] = v;
        else           xr[(size_t)row * 128 + (col - 128)] = v;
      }
    }
}

// ---------------------------------------------------------------------------
// Node pass (PROVEN 47.6 us config): one wave per node; 2 edges/pass;
// lane&31 owns dims 4hl..4hl+3; head reduce = shfl 1,2,4; exp2; 28 VGPR.
// Latency hidden by TLP — do NOT add register batching (r13/r14 regressed).
// ---------------------------------------------------------------------------
__global__ __launch_bounds__(256) void node_kernel(const unsigned int* __restrict__ xl32,
                                                   const unsigned int* __restrict__ xr32,
                                                   const float* __restrict__ att,
                                                   const float* __restrict__ bias,
                                                   const int* __restrict__ off,
                                                   const int* __restrict__ csr,
                                                   unsigned int* __restrict__ fout, int n) {
  int wid = threadIdx.x >> 6, lane = threadIdx.x & 63;
  int node = blockIdx.x * 4 + wid;
  if (node >= n) return;
  int hl = lane & 31;
  bool upper = lane >= 32;
  const float LOG2E = 1.44269504f;
  float4 av = *(const float4*)(att + hl * 4);
  float a0 = av.x * LOG2E, a1 = av.y * LOG2E, a2 = av.z * LOG2E, a3 = av.w * LOG2E;
  uint2 xrp = *(const uint2*)(xr32 + node * 64 + hl * 2);
  float xr0 = blo(xrp.x), xr1 = bhi(xrp.x);
  float xr2 = blo(xrp.y), xr3 = bhi(xrp.y);
  float num0 = 0.f, num1 = 0.f, num2 = 0.f, num3 = 0.f, den = 0.f;
  int beg = off[node], end = off[node + 1];

  auto edge2 = [&](int sLo, int sHi, bool hiValid) {
    int s = upper ? sHi : sLo;
    uint2 g = *(const uint2*)(xl32 + ((unsigned)s << 6) + (unsigned)(hl << 1));
    float x0 = blo(g.x), x1 = bhi(g.x), x2 = blo(g.y), x3 = bhi(g.y);
    float m0 = x0 + xr0, m1 = x1 + xr1, m2 = x2 + xr2, m3 = x3 + xr3;
    float l0 = fmaxf(m0, 0.2f * m0), l1 = fmaxf(m1, 0.2f * m1);
    float l2 = fmaxf(m2, 0.2f * m2), l3 = fmaxf(m3, 0.2f * m3);
    float p = l0 * a0;
    p = fmaf(l1, a1, p);
    p = fmaf(l2, a2, p);
    p = fmaf(l3, a3, p);
    p += __shfl_xor(p, 1, 64);
    p += __shfl_xor(p, 2, 64);
    p += __shfl_xor(p, 4, 64);
    float wgt = __builtin_amdgcn_exp2f(p);
    if (upper && !hiValid) wgt = 0.f;
    num0 = fmaf(wgt, x0, num0);
    num1 = fmaf(wgt, x1, num1);
    num2 = fmaf(wgt, x2, num2);
    num3 = fmaf(wgt, x3, num3);
    den += wgt;
  };

  if (beg < end) {
    edge2(node, csr[beg], true);          // self loop paired with first edge
    for (int base = beg + 1; base < end; base += 64) {
      int cnt = end - base;
      if (cnt > 64) cnt = 64;
      int my = csr[base + (lane < cnt ? lane : 0)];
      int i = 0;
      for (; i + 4 <= cnt; i += 4) {
        int sa = __builtin_amdgcn_readlane(my, i);
        int sb = __builtin_amdgcn_readlane(my, i + 1);
        int sc = __builtin_amdgcn_readlane(my, i + 2);
        int sd = __builtin_amdgcn_readlane(my, i + 3);
        edge2(sa, sb, true);
        edge2(sc, sd, true);
      }
      for (; i + 2 <= cnt; i += 2) {
        int sa = __builtin_amdgcn_readlane(my, i);
        int sb = __builtin_amdgcn_readlane(my, i + 1);
        edge2(sa, sb, true);
      }
      if (i < cnt) edge2(__builtin_amdgcn_readlane(my, i), node, false);
    }
  } else {
    edge2(node, node, false);             // isolated node: self loop only
  }

  num0 += __shfl_xor(num0, 32, 64);
  num1 += __shfl_xor(num1, 32, 64);
  num2 += __shfl_xor(num2, 32, 64);
  num3 += __shfl_xor(num3, 32, 64);
  den  += __shfl_xor(den, 32, 64);

  if (!upper) {
    float inv = 1.f / (den + 1e-16f);
    float4 bv = *(const float4*)(bias + hl * 4);
    float v0 = num0 * inv + bv.x;
    float v1 = num1 * inv + bv.y;
    float v2 = num2 * inv + bv.z;
    float v3 = num3 * inv + bv.w;
    uint2 o;
    o.x = (unsigned)f2b(sigm(v0)) | ((unsigned)f2b(sigm(v1)) << 16);
    o.y = (unsigned)f2b(sigm(v2)) | ((unsigned)f2b(sigm(v3)) << 16);
    *(uint2*)(fout + node * 64 + hl * 2) = o;
  }
}

// ---------------------------------------------------------------------------
// Fused GRU GEMMs.  BM=32, LDS = A only (16 KB), 1563 blocks.
// B fragments from L2 with one-step register double-buffer.
// Phase1 wave w: cols {w*32..} U {128+w*32..} -> u gate stays in registers.
// ---------------------------------------------------------------------------
__global__ __launch_bounds__(256) void gemm_fused(const unsigned short* __restrict__ fbuf,
                                                  const float* __restrict__ hf,
                                                  const unsigned short* __restrict__ Btf1,
                                                  const unsigned short* __restrict__ Btf2,
                                                  const float* __restrict__ b1,
                                                  const float* __restrict__ b2,
                                                  float* __restrict__ out, int n) {
  __shared__ char As[32 * 512];           // [f|h] 32 rows x 256 bf16, swizzled
  int t = threadIdx.x;
  int w = t >> 6, l = t & 63;
  int row0 = blockIdx.x * 32;
  int l15 = l & 15, lhi = l >> 4;

  // stage A = [f | h]: src linear, dest swizzled
  #pragma unroll
  for (int u_ = 0; u_ < 4; ++u_) {
    int unit = t + u_ * 256;
    int r = unit >> 5, slot = unit & 31;
    int koff = slot * 16;
    int grow = row0 + r;
    uint4 v = make_uint4(0, 0, 0, 0);
    if (grow < n) {
      if (koff < 256) {
        v = *(const uint4*)(fbuf + (size_t)grow * 128 + koff / 2);
      } else {
        const float* s = hf + (size_t)grow * 128 + (koff - 256) / 2;
        float4 f0 = *(const float4*)s, f1 = *(const float4*)(s + 4);
        v.x = (unsigned)f2b(f0.x) | ((unsigned)f2b(f0.y) << 16);
        v.y = (unsigned)f2b(f0.z) | ((unsigned)f2b(f0.w) << 16);
        v.z = (unsigned)f2b(f1.x) | ((unsigned)f2b(f1.y) << 16);
        v.w = (unsigned)f2b(f1.z) | ((unsigned)f2b(f1.w) << 16);
      }
    }
    *(uint4*)(As + r * 512 + (koff ^ ((r & 7) << 4))) = v;
  }
  __syncthreads();

  // ---- phase 1: K=256, N=256; 8 steps of K=32 ----
  floatx4 acc[2][4];
  #pragma unroll
  for (int mt = 0; mt < 2; ++mt)
    #pragma unroll
    for (int nt = 0; nt < 4; ++nt) acc[mt][nt] = (floatx4){0.f, 0.f, 0.f, 0.f};

  short8 bcur[4], bnext[4];
  #pragma unroll
  for (int nt = 0; nt < 4; ++nt)
    bcur[nt] = *(const short8*)(Btf1 + (((size_t)(w * 4 + nt) * 8 + 0) * 64 + l) * 8);

  #pragma unroll 1
  for (int step = 0; step < 8; ++step) {
    if (step < 7) {
      #pragma unroll
      for (int nt = 0; nt < 4; ++nt)
        bnext[nt] = *(const short8*)(Btf1 + (((size_t)(w * 4 + nt) * 8 + step + 1) * 64 + l) * 8);
    }
    int ka = step * 64 + lhi * 16;
    short8 a[2];
    #pragma unroll
    for (int mt = 0; mt < 2; ++mt) {
      int r = mt * 16 + l15;
      a[mt] = *(const short8*)(As + r * 512 + (ka ^ ((r & 7) << 4)));
    }
    #pragma unroll
    for (int nt = 0; nt < 4; ++nt)
      #pragma unroll
      for (int mt = 0; mt < 2; ++mt)
        acc[mt][nt] = __builtin_amdgcn_mfma_f32_16x16x32_bf16(a[mt], bcur[nt], acc[mt][nt], 0, 0, 0);
    if (step < 7) {
      #pragma unroll
      for (int nt = 0; nt < 4; ++nt) bcur[nt] = bnext[nt];
    }
  }
  __syncthreads();   // all waves done reading As (h half) before overwrite

  // phase-1 epilogue: r-cols -> rh overwrites h half of As (swizzled);
  // u-cols stay in registers (layout matches phase-2 accumulator).
  float us[2][2][4];
  #pragma unroll
  for (int mt = 0; mt < 2; ++mt)
    #pragma unroll
    for (int nt = 0; nt < 4; ++nt) {
      #pragma unroll
      for (int j = 0; j < 4; ++j) {
        int rloc = mt * 16 + lhi * 4 + j;
        if (nt < 2) {
          int col = w * 32 + nt * 16 + l15;
          float s = sigm(acc[mt][nt][j] + b1[col]);
          int byteoff = (256 + col * 2) ^ ((rloc & 7) << 4);
          char* p = As + rloc * 512 + byteoff;
          unsigned short hv = *(unsigned short*)p;
          *(unsigned short*)p = f2b(s * b2f(hv));
        } else {
          int col = 128 + w * 32 + (nt - 2) * 16 + l15;
          us[mt][nt - 2][j] = sigm(acc[mt][nt][j] + b1[col]);
        }
      }
    }
  __syncthreads();

  // ---- phase 2: K=256, N=128; wave w owns cols w*32..+31 ----
  floatx4 acc2[2][2];
  #pragma unroll
  for (int mt = 0; mt < 2; ++mt)
    #pragma unroll
    for (int nt = 0; nt < 2; ++nt) acc2[mt][nt] = (floatx4){0.f, 0.f, 0.f, 0.f};

  short8 bcur2[2], bnext2[2];
  #pragma unroll
  for (int nt = 0; nt < 2; ++nt)
    bcur2[nt] = *(const short8*)(Btf2 + (((size_t)(w * 2 + nt) * 8 + 0) * 64 + l) * 8);

  #pragma unroll 1
  for (int step = 0; step < 8; ++step) {
    if (step < 7) {
      #pragma unroll
      for (int nt = 0; nt < 2; ++nt)
        bnext2[nt] = *(const short8*)(Btf2 + (((size_t)(w * 2 + nt) * 8 + step + 1) * 64 + l) * 8);
    }
    int ka = step * 64 + lhi * 16;
    short8 a[2];
    #pragma unroll
    for (int mt = 0; mt < 2; ++mt) {
      int r = mt * 16 + l15;
      a[mt] = *(const short8*)(As + r * 512 + (ka ^ ((r & 7) << 4)));
    }
    #pragma unroll
    for (int nt = 0; nt < 2; ++nt)
      #pragma unroll
      for (int mt = 0; mt < 2; ++mt)
        acc2[mt][nt] = __builtin_amdgcn_mfma_f32_16x16x32_bf16(a[mt], bcur2[nt], acc2[mt][nt], 0, 0, 0);
    if (step < 7) {
      #pragma unroll
      for (int nt = 0; nt < 2; ++nt) bcur2[nt] = bnext2[nt];
    }
  }

  #pragma unroll
  for (int mt = 0; mt < 2; ++mt)
    #pragma unroll
    for (int nt = 0; nt < 2; ++nt) {
      int col = w * 32 + nt * 16 + l15;
      #pragma unroll
      for (int j = 0; j < 4; ++j) {
        int rloc = mt * 16 + lhi * 4 + j;
        int row = row0 + rloc;
        if (row >= n) continue;
        float c = tanh_fast(acc2[mt][nt][j] + b2[col]);
        float uu = us[mt][nt][j];
        float hv = hf[(size_t)row * 128 + col];
        out[(size_t)row * 128 + col] = uu * hv + (1.f - uu) * c;
      }
    }
}

extern "C" void kernel_launch(void* const* d_in, const int* in_sizes, int n_in,
                              void* d_out, int out_size, void* d_ws, size_t ws_size,
                              hipStream_t stream) {
  const float* x     = (const float*)d_in[0];
  const void*  ei    = d_in[1];
  const float* h     = (const float*)d_in[3];
  const float* Wl    = (const float*)d_in[4];
  const float* Wr    = (const float*)d_in[5];
  const float* att   = (const float*)d_in[6];
  const float* bconv = (const float*)d_in[7];
  const float* W1    = (const float*)d_in[8];
  const float* b1    = (const float*)d_in[9];
  const float* W2    = (const float*)d_in[10];
  const float* b2    = (const float*)d_in[11];
  float* out = (float*)d_out;

  const int n = in_sizes[0] / 128;   // 50000
  const int E = in_sizes[1] / 2;     // 800000
  const int nbk = (n + 127) >> 7;    // 391

  char* w = (char*)d_ws;
  size_t o = 0;
  auto alloc = [&](size_t bytes) {
    char* p = w + o;
    o += bytes;
    o = (o + 255) & ~(size_t)255;
    return p;
  };
  int* bucketCnt    = (int*)alloc((size_t)nbk * 4);
  int* bucketBase   = (int*)alloc((size_t)(nbk + 1) * 4);
  int* bucketCursor = (int*)alloc((size_t)nbk * 4);
  int* off          = (int*)alloc((size_t)(n + 1) * 4);
  int* csr          = (int*)alloc((size_t)E * 4);
  unsigned long long* pairBuf = (unsigned long long*)alloc((size_t)E * 8);
  unsigned short* xl   = (unsigned short*)alloc((size_t)n * 128 * 2);
  unsigned short* xr   = (unsigned short*)alloc((size_t)n * 128 * 2);
  unsigned short* fbuf = (unsigned short*)alloc((size_t)n * 128 * 2);
  unsigned short* Btfxw = (unsigned short*)alloc(4096 * 8 * 2);
  unsigned short* Btf1  = (unsigned short*)alloc(8192 * 8 * 2);
  unsigned short* Btf2  = (unsigned short*)alloc(4096 * 8 * 2);

  int gblocks = (n + 31) / 32;       // 1563

  hipMemsetAsync(bucketCnt, 0, (size_t)nbk * 4, stream);
  prep1<<<320, 256, 0, stream>>>(ei, E, bucketCnt, nbk, Wl, Wr, W1, W2, Btfxw, Btf1, Btf2);
  bucket_scan<<<1, 64, 0, stream>>>(bucketCnt, bucketBase, bucketCursor, nbk);
  partition_kernel<<<(E + 4095) / 4096, 256, 0, stream>>>(ei, E, bucketCursor, pairBuf, nbk);
  csr_xw<<<nbk + gblocks, 256, 0, stream>>>(pairBuf, bucketBase, off, csr, n, E, nbk,
                                            x, Btfxw, xl, xr);
  node_kernel<<<(n + 3) / 4, 256, 0, stream>>>((const unsigned int*)xl, (const unsigned int*)xr,
                                               att, bconv, off, csr,
                                               (unsigned int*)fbuf, n);
  gemm_fused<<<gblocks, 256, 0, stream>>>(fbuf, h, Btf1, Btf2, b1, b2, out, n);
}